// Round 1
// 2648.480 us; speedup vs baseline: 1.6258x; 1.6258x over previous
//
#include <hip/hip_runtime.h>

#define T_STEPS 512
#define NTHREADS 1024          // 16 waves, 4 per SIMD (was 4 waves, 1/SIMD)
#define EPSF 1e-6f
#define BASE_LR_F 0.01f

__device__ __forceinline__ float lane_bcast(float v, int l) {
    return __int_as_float(__builtin_amdgcn_readlane(__float_as_int(v), l));
}

// 64-lane sum: butterfly masks 16..1 (inside 32-lane halves), combine halves
// via readlane(0)+readlane(32).
__device__ __forceinline__ float wave_sum1(float a) {
    #pragma unroll
    for (int m = 16; m >= 1; m >>= 1) a += __shfl_xor(a, m, 64);
    return lane_bcast(a, 0) + lane_bcast(a, 32);
}
__device__ __forceinline__ void wave_sum2(float &a, float &b) {
    #pragma unroll
    for (int m = 16; m >= 1; m >>= 1) {
        a += __shfl_xor(a, m, 64);
        b += __shfl_xor(b, m, 64);
    }
    a = lane_bcast(a, 0) + lane_bcast(a, 32);
    b = lane_bcast(b, 0) + lane_bcast(b, 32);
}

struct SMem {
    float W[64][64];                    // W[d][f]  (stride-1 over f: conflict-free)
    float b1s[64];
    __align__(16) float xk[16][68];     // row-major, +4 pad
    __align__(16) float xq[16][68];
    __align__(16) float gz[16][68];
    __align__(16) float eta[16];
};

__global__ __launch_bounds__(NTHREADS, 4) void ttt_kernel(
    const float* __restrict__ XQ, const float* __restrict__ XK,
    const float* __restrict__ XV, const float* __restrict__ W1,
    const float* __restrict__ b1, const float* __restrict__ gamma,
    const float* __restrict__ beta, float* __restrict__ OUT)
{
    __shared__ SMem sm;

    const int bh  = blockIdx.x;        // b*16 + h
    const int h   = bh & 15;
    const int tid = threadIdx.x;
    const int f   = tid & 63;          // feature column
    const int q   = tid >> 6;          // wave id == k-row id (16 waves, 16 rows)

    // zero ALL LDS (no dependence on stale LDS)
    {
        float* zp = (float*)&sm;
        const int nflt = (int)(sizeof(SMem) / 4);
        for (int i = tid; i < nflt; i += NTHREADS) zp[i] = 0.0f;
    }
    __syncthreads();

    for (int i = tid; i < 4096; i += NTHREADS)
        sm.W[i >> 6][i & 63] = W1[h * 4096 + i];
    if (tid < 64) sm.b1s[tid] = b1[h * 64 + tid];
    const float g_f  = gamma[h * 64 + f];
    const float be_f = beta[h * 64 + f];

    const int base   = bh * (T_STEPS * 1024);
    const int rowoff = q * 64 + f;

    float xkr = XK[base + rowoff];
    float xqr = XQ[base + rowoff];
    float xvr = XV[base + rowoff];
    float nxk = 0.0f, nxq = 0.0f, nxv = 0.0f;

    __syncthreads();

    for (int t = 0; t < T_STEPS; ++t) {
        // software prefetch next step (consumed at loop bottom)
        if (t + 1 < T_STEPS) {
            const int o1 = base + (t + 1) * 1024 + rowoff;
            nxk = XK[o1]; nxq = XQ[o1]; nxv = XV[o1];
        }

        // ---- stage xk,xq rows; per-row eta ----
        sm.xk[q][f] = xkr;
        sm.xq[q][f] = xqr;
        {
            const float s = wave_sum1(xkr * xkr);
            if (f == 0) {
                const float nrm = fmaxf(sqrtf(s), EPSF);
                sm.eta[q] = BASE_LR_F / (1.0f + nrm);
            }
        }
        __syncthreads();                                  // B1

        // em / el (float4 broadcast reads of eta[16])
        float em, el;
        {
            const float4 e0 = *(const float4*)&sm.eta[0];
            const float4 e1 = *(const float4*)&sm.eta[4];
            const float4 e2 = *(const float4*)&sm.eta[8];
            const float4 e3 = *(const float4*)&sm.eta[12];
            em = ((e0.x+e0.y+e0.z+e0.w) + (e1.x+e1.y+e1.z+e1.w)
                + (e2.x+e2.y+e2.z+e2.w) + (e3.x+e3.y+e3.z+e3.w)) * (1.0f/16.0f);
            el = e3.w;
        }
        const float bb = sm.b1s[f];
        // pre-read xk row15 block for the post-B2 W update (keeps xk single-buffered)
        const float4 xk15b = *(const float4*)&sm.xk[15][4 * q];

        // ---- fused matmuls: acc = xk_q@W + bb (Z1), accd = xq_q@W ----
        // one conflict-free W[d][f] read feeds 2 FMAs; xk/xq via float4 broadcast
        float acc  = bb;
        float accd = 0.0f;
        #pragma unroll
        for (int i = 0; i < 16; ++i) {
            const float4 k4 = *(const float4*)&sm.xk[q][4 * i];
            const float4 q4 = *(const float4*)&sm.xq[q][4 * i];
            const float w0 = sm.W[4*i+0][f];
            const float w1 = sm.W[4*i+1][f];
            const float w2 = sm.W[4*i+2][f];
            const float w3 = sm.W[4*i+3][f];
            acc  = fmaf(k4.x, w0, acc );  accd = fmaf(q4.x, w0, accd);
            acc  = fmaf(k4.y, w1, acc );  accd = fmaf(q4.y, w1, accd);
            acc  = fmaf(k4.z, w2, acc );  accd = fmaf(q4.z, w2, accd);
            acc  = fmaf(k4.w, w3, acc );  accd = fmaf(q4.w, w3, accd);
        }

        // ---- A row q in-register: lane (kk=f&15, tt=f>>4) quarter-dot ----
        // coef_kk = em*(1 + Araw[q][kk]) folds both -A@gz and b1u's -em*sum(gz)
        float coef;
        {
            const int kk = f & 15, tt = f >> 4;
            float a = 0.0f;
            #pragma unroll
            for (int c = 0; c < 4; ++c) {
                const float4 xq4 = *(const float4*)&sm.xq[q][16 * tt + 4 * c];
                const float4 xk4 = *(const float4*)&sm.xk[kk][16 * tt + 4 * c];
                a = fmaf(xq4.x, xk4.x, a); a = fmaf(xq4.y, xk4.y, a);
                a = fmaf(xq4.z, xk4.z, a); a = fmaf(xq4.w, xk4.w, a);
            }
            a += __shfl_xor(a, 16, 64);
            a += __shfl_xor(a, 32, 64);   // every lane: full Araw[q][f&15]
            coef = em * (1.0f + a);
        }

        // ---- ln(Z1) -> gz row ----
        {
            float s1 = acc, s2 = acc * acc;
            wave_sum2(s1, s2);
            const float mu  = s1 * (1.0f/64.0f);
            const float var = s2 * (1.0f/64.0f) - mu * mu;
            const float inv = rsqrtf(var + EPSF);
            const float lnv = g_f * ((acc - mu) * inv) + be_f;
            sm.gz[q][f] = 2.0f * (lnv - (xvr - xkr));
        }
        __syncthreads();                                  // B2

        // ---- Z1d = xq@W1c + b1u - A@gz  (rank-16 correction) ----
        float zd = accd + bb;
        #pragma unroll
        for (int kk = 0; kk < 16; ++kk)
            zd = fmaf(-lane_bcast(coef, kk), sm.gz[kk][f], zd);

        // ---- out = xq + ln(Z1d) ----
        {
            float s1 = zd, s2 = zd * zd;
            wave_sum2(s1, s2);
            const float mu  = s1 * (1.0f/64.0f);
            const float var = s2 * (1.0f/64.0f) - mu * mu;
            const float inv = rsqrtf(var + EPSF);
            const float lnv = g_f * ((zd - mu) * inv) + be_f;
            OUT[base + t * 1024 + rowoff] = xqr + lnv;
        }

        // ---- carry rank-1 update: wave q owns d-rows 4q..4q+3 ----
        // (writes W post-B2; next read is post-B1(t+1) -> no extra barrier)
        {
            const float c2 = el * sm.gz[15][f];
            sm.W[4*q+0][f] = fmaf(-xk15b.x, c2, sm.W[4*q+0][f]);
            sm.W[4*q+1][f] = fmaf(-xk15b.y, c2, sm.W[4*q+1][f]);
            sm.W[4*q+2][f] = fmaf(-xk15b.z, c2, sm.W[4*q+2][f]);
            sm.W[4*q+3][f] = fmaf(-xk15b.w, c2, sm.W[4*q+3][f]);
            if (q == 0) sm.b1s[f] = bb - c2;
        }

        xkr = nxk; xqr = nxq; xvr = nxv;
    }   // only 2 barriers per step (was 4)
}

extern "C" void kernel_launch(void* const* d_in, const int* in_sizes, int n_in,
                              void* d_out, int out_size, void* d_ws, size_t ws_size,
                              hipStream_t stream) {
    const float* XQ    = (const float*)d_in[0];
    const float* XK    = (const float*)d_in[1];
    const float* XV    = (const float*)d_in[2];
    const float* W1    = (const float*)d_in[3];
    const float* b1    = (const float*)d_in[4];
    const float* gamma = (const float*)d_in[5];
    const float* beta  = (const float*)d_in[6];
    float* OUT = (float*)d_out;
    ttt_kernel<<<dim3(64), dim3(NTHREADS), 0, stream>>>(
        XQ, XK, XV, W1, b1, gamma, beta, OUT);
}

// Round 2
// 2461.306 us; speedup vs baseline: 1.7494x; 1.0760x over previous
//
#include <hip/hip_runtime.h>

#define T_STEPS 512
#define NTHREADS 1024          // 16 waves, 4 per SIMD
#define EPSF 1e-6f
#define BASE_LR_F 0.01f

__device__ __forceinline__ float lane_bcast(float v, int l) {
    return __int_as_float(__builtin_amdgcn_readlane(__float_as_int(v), l));
}

// 64-lane sum: butterfly masks 16..1 (inside 32-lane halves), combine halves
// via readlane(0)+readlane(32).
__device__ __forceinline__ float wave_sum1(float a) {
    #pragma unroll
    for (int m = 16; m >= 1; m >>= 1) a += __shfl_xor(a, m, 64);
    return lane_bcast(a, 0) + lane_bcast(a, 32);
}
__device__ __forceinline__ void wave_sum2(float &a, float &b) {
    #pragma unroll
    for (int m = 16; m >= 1; m >>= 1) {
        a += __shfl_xor(a, m, 64);
        b += __shfl_xor(b, m, 64);
    }
    a = lane_bcast(a, 0) + lane_bcast(a, 32);
    b = lane_bcast(b, 0) + lane_bcast(b, 32);
}

struct SMem {
    __align__(16) float xk[16][68];     // row-major, +4 pad
    __align__(16) float xq[16][68];
    __align__(16) float gz[16][68];
    __align__(16) float xk15c[2][64];   // double-buffered copy of xk row 15
    __align__(16) float eta[16];
};

__global__ __launch_bounds__(NTHREADS, 4) void ttt_kernel(
    const float* __restrict__ XQ, const float* __restrict__ XK,
    const float* __restrict__ XV, const float* __restrict__ W1,
    const float* __restrict__ b1, const float* __restrict__ gamma,
    const float* __restrict__ beta, float* __restrict__ OUT)
{
    __shared__ SMem sm;

    const int bh  = blockIdx.x;        // b*16 + h
    const int h   = bh & 15;
    const int tid = threadIdx.x;
    const int f   = tid & 63;          // feature column
    const int q   = tid >> 6;          // wave id == k-row id

    // zero ALL LDS (no dependence on stale LDS)
    {
        float* zp = (float*)&sm;
        const int nflt = (int)(sizeof(SMem) / 4);
        for (int i = tid; i < nflt; i += NTHREADS) zp[i] = 0.0f;
    }

    // ---- W column f -> 64 VGPRs per lane; b1/gamma/beta -> regs ----
    // Each instruction below is a fully-coalesced 256B load (lanes contiguous).
    float Wreg[64];
    #pragma unroll
    for (int d = 0; d < 64; ++d) Wreg[d] = W1[h * 4096 + d * 64 + f];
    float b1r = b1[h * 64 + f];        // identical copy maintained per wave
    const float g_f  = gamma[h * 64 + f];
    const float be_f = beta[h * 64 + f];

    const int base   = bh * (T_STEPS * 1024);
    const int rowoff = q * 64 + f;

    float xkr = XK[base + rowoff];
    float xqr = XQ[base + rowoff];
    float xvr = XV[base + rowoff];
    float nxk = 0.0f, nxq = 0.0f, nxv = 0.0f;

    __syncthreads();

    for (int t = 0; t < T_STEPS; ++t) {
        // software prefetch next step (consumed at loop bottom)
        if (t + 1 < T_STEPS) {
            const int o1 = base + (t + 1) * 1024 + rowoff;
            nxk = XK[o1]; nxq = XQ[o1]; nxv = XV[o1];
        }

        // ---- stage xk,xq rows; per-row eta; xk15 copy (dbuf, read post-B2) ----
        sm.xk[q][f] = xkr;
        sm.xq[q][f] = xqr;
        if (q == 15) sm.xk15c[t & 1][f] = xkr;
        {
            const float s = wave_sum1(xkr * xkr);
            if (f == 0) {
                const float nrm = fmaxf(sqrtf(s), EPSF);
                sm.eta[q] = BASE_LR_F / (1.0f + nrm);
            }
        }
        __syncthreads();                                  // B1

        // em / el (float4 broadcast reads of eta[16])
        float em, el;
        {
            const float4 e0 = *(const float4*)&sm.eta[0];
            const float4 e1 = *(const float4*)&sm.eta[4];
            const float4 e2 = *(const float4*)&sm.eta[8];
            const float4 e3 = *(const float4*)&sm.eta[12];
            em = ((e0.x+e0.y+e0.z+e0.w) + (e1.x+e1.y+e1.z+e1.w)
                + (e2.x+e2.y+e2.z+e2.w) + (e3.x+e3.y+e3.z+e3.w)) * (1.0f/16.0f);
            el = e3.w;
        }

        // ---- fused matmuls from registers: acc = xk_q@W, accd = xq_q@W ----
        // x operands via broadcast float4 LDS reads; W per-lane VGPRs.
        // 2 accumulator chains each (dep chain 32 FMA).
        float ac0 = 0.0f, ac1 = 0.0f, ad0 = 0.0f, ad1 = 0.0f;
        #pragma unroll
        for (int i = 0; i < 16; ++i) {
            const float4 k4 = *(const float4*)&sm.xk[q][4 * i];
            const float4 q4 = *(const float4*)&sm.xq[q][4 * i];
            if (i & 1) {
                ac1 = fmaf(k4.x, Wreg[4*i+0], ac1); ad1 = fmaf(q4.x, Wreg[4*i+0], ad1);
                ac1 = fmaf(k4.y, Wreg[4*i+1], ac1); ad1 = fmaf(q4.y, Wreg[4*i+1], ad1);
                ac1 = fmaf(k4.z, Wreg[4*i+2], ac1); ad1 = fmaf(q4.z, Wreg[4*i+2], ad1);
                ac1 = fmaf(k4.w, Wreg[4*i+3], ac1); ad1 = fmaf(q4.w, Wreg[4*i+3], ad1);
            } else {
                ac0 = fmaf(k4.x, Wreg[4*i+0], ac0); ad0 = fmaf(q4.x, Wreg[4*i+0], ad0);
                ac0 = fmaf(k4.y, Wreg[4*i+1], ac0); ad0 = fmaf(q4.y, Wreg[4*i+1], ad0);
                ac0 = fmaf(k4.z, Wreg[4*i+2], ac0); ad0 = fmaf(q4.z, Wreg[4*i+2], ad0);
                ac0 = fmaf(k4.w, Wreg[4*i+3], ac0); ad0 = fmaf(q4.w, Wreg[4*i+3], ad0);
            }
        }
        const float acc  = b1r + (ac0 + ac1);
        const float accd = ad0 + ad1;

        // ---- A row q in-register: lane (kk=f&15, tt=f>>4) quarter-dot ----
        // coef_kk = em*(1 + Araw[q][kk]) folds -A@gz and b1u's -em*sum(gz)
        float coef;
        {
            const int kk = f & 15, tt = f >> 4;
            float a = 0.0f;
            #pragma unroll
            for (int c = 0; c < 4; ++c) {
                const float4 xq4 = *(const float4*)&sm.xq[q][16 * tt + 4 * c];
                const float4 xk4 = *(const float4*)&sm.xk[kk][16 * tt + 4 * c];
                a = fmaf(xq4.x, xk4.x, a); a = fmaf(xq4.y, xk4.y, a);
                a = fmaf(xq4.z, xk4.z, a); a = fmaf(xq4.w, xk4.w, a);
            }
            a += __shfl_xor(a, 16, 64);
            a += __shfl_xor(a, 32, 64);   // every lane: full Araw[q][f&15]
            coef = em * (1.0f + a);
        }

        // ---- ln(Z1) -> gz row ----
        {
            float s1 = acc, s2 = acc * acc;
            wave_sum2(s1, s2);
            const float mu  = s1 * (1.0f/64.0f);
            const float var = s2 * (1.0f/64.0f) - mu * mu;
            const float inv = rsqrtf(var + EPSF);
            const float lnv = g_f * ((acc - mu) * inv) + be_f;
            sm.gz[q][f] = 2.0f * (lnv - (xvr - xkr));
        }
        __syncthreads();                                  // B2

        // ---- Z1d = xq@W1c + b1u - A@gz  (rank-16 correction) ----
        float zd = accd + b1r;
        #pragma unroll
        for (int kk = 0; kk < 16; ++kk)
            zd = fmaf(-lane_bcast(coef, kk), sm.gz[kk][f], zd);

        // ---- out = xq + ln(Z1d) ----
        {
            float s1 = zd, s2 = zd * zd;
            wave_sum2(s1, s2);
            const float mu  = s1 * (1.0f/64.0f);
            const float var = s2 * (1.0f/64.0f) - mu * mu;
            const float inv = rsqrtf(var + EPSF);
            const float lnv = g_f * ((zd - mu) * inv) + be_f;
            OUT[base + t * 1024 + rowoff] = xqr + lnv;
        }

        // ---- carry rank-1 update in registers: W -= el * xk15 (x) gz15 ----
        // gz15 read is post-B2-safe (next write is after B1(t+1));
        // xk15 comes from the parity buffer written this step (next overwrite
        // is at t+2, two barriers away).
        {
            const float c2 = el * sm.gz[15][f];
            #pragma unroll
            for (int i = 0; i < 16; ++i) {
                const float4 x4 = *(const float4*)&sm.xk15c[t & 1][4 * i];
                Wreg[4*i+0] = fmaf(-x4.x, c2, Wreg[4*i+0]);
                Wreg[4*i+1] = fmaf(-x4.y, c2, Wreg[4*i+1]);
                Wreg[4*i+2] = fmaf(-x4.z, c2, Wreg[4*i+2]);
                Wreg[4*i+3] = fmaf(-x4.w, c2, Wreg[4*i+3]);
            }
            b1r -= c2;
        }

        xkr = nxk; xqr = nxq; xvr = nxv;
    }   // 2 barriers per step; W/b1 carry entirely in registers
}

extern "C" void kernel_launch(void* const* d_in, const int* in_sizes, int n_in,
                              void* d_out, int out_size, void* d_ws, size_t ws_size,
                              hipStream_t stream) {
    const float* XQ    = (const float*)d_in[0];
    const float* XK    = (const float*)d_in[1];
    const float* XV    = (const float*)d_in[2];
    const float* W1    = (const float*)d_in[3];
    const float* b1    = (const float*)d_in[4];
    const float* gamma = (const float*)d_in[5];
    const float* beta  = (const float*)d_in[6];
    float* OUT = (float*)d_out;
    ttt_kernel<<<dim3(64), dim3(NTHREADS), 0, stream>>>(
        XQ, XK, XV, W1, b1, gamma, beta, OUT);
}